// Round 9
// baseline (1716.902 us; speedup 1.0000x reference)
//
#include <hip/hip_runtime.h>

// Persistent-CG, full-row decomposition. R8 post-mortem: traffic fixed (FETCH
// 102MB = K once; r broadcast L3-served) but dur unchanged 1604us. Cause: r
// broadcast used sc1 BYPASS loads -> no L1/L2 aggregation, 68MB/iter of raw
// 16B requests at the coherence point = 2.0 TB/s measured sustain = the limit.
// R9: cross-block READS go on the cached path (L2 34.5 TB/s agg, per-XCD refill
// from L3 only 0.33MB/iter); safety = one acquire fence (inv) per block per
// gridbar exit (L2 only ever holds CLEAN stale copies since all cross-block
// WRITES remain sc1 write-through -> no wbl2 needed, R6-verified). Also: finish
// LDS atomics -> per-wave wq staging (kills 26.5M bank-conflict cycles), slab
// staging stride 32B->16B (conflict-free b128 writes).

#define NN   4096
#define TT   17
#define PP   16
#define NTOT (NN*TT)
#define NIT  47
#define NBLK 256              // 1 block/CU, cooperative co-residency
#define NTHR 512              // 8 waves
#define EPB  272              // 17 cols x 16 own rows

// ws float offsets
#define O_SSQ  0                    // [16][64] setup ssq partials (sc1-written)
#define O_SLOT (O_SSQ + 16*64)      // [256][64] dot slots (sc1-written, cached-read)
#define O_BAR  (O_SLOT + NBLK*64)   // flags[256] + go replicas at 256+32*i
#define O_R    (O_BAR + 576)        // r (sc1-written, cached-read)

#define AGENT __HIP_MEMORY_SCOPE_AGENT
#define RLX   __ATOMIC_RELAXED

typedef float f32x4 __attribute__((ext_vector_type(4)));

__global__ void k_bzero(float* __restrict__ ws) {
    if (threadIdx.x < 576) ((unsigned*)(ws + O_BAR))[threadIdx.x] = 0u;
}

// Store-only monotonic grid barrier (R6-verified) + ONE acquire fence (inv) at
// exit: invalidates CU-L1 + XCD-L2 so post-barrier cached reads of sc1-written
// data (r, slots) refetch from the coherence point. No release fence needed:
// cross-block writes are sc1 write-through, L2 never holds them dirty.
__device__ __forceinline__ void gridbar(unsigned* bar, int phase, int b) {
    const unsigned target = (unsigned)(phase + 1);
    asm volatile("s_waitcnt vmcnt(0)" ::: "memory");   // sc1 stores at L3
    __syncthreads();
    if (b == 0) {
        if (threadIdx.x >= 1 && threadIdx.x < NBLK) {
            while (__hip_atomic_load(&bar[threadIdx.x], RLX, AGENT) < target)
                __builtin_amdgcn_s_sleep(1);
        }
        __syncthreads();
        if (threadIdx.x < 8)
            __hip_atomic_store(&bar[256 + threadIdx.x*32], target, RLX, AGENT);
    } else {
        if (threadIdx.x == 0) {
            __hip_atomic_store(&bar[b], target, RLX, AGENT);
            while (__hip_atomic_load(&bar[256 + (b & 7)*32], RLX, AGENT) < target)
                __builtin_amdgcn_s_sleep(1);
        }
    }
    __syncthreads();
    if (threadIdx.x == 0)
        __builtin_amdgcn_fence(__ATOMIC_ACQUIRE, "agent");  // inv L1 + XCD-L2
    __syncthreads();
}

__global__ __launch_bounds__(NTHR, 2)
void k_cg(const float* __restrict__ Km, const float* __restrict__ yv,
          const float* __restrict__ Zm, const float* __restrict__ noise,
          float* __restrict__ out, float* __restrict__ ws) {
    __shared__ __align__(16) float rslab[2][NN];     // 32 KB r col double-buffer
    __shared__ float4 p2a[8*TT*17];                  // wave partials rows 0-3
    __shared__ float4 p2b[8*TT*17];                  // rows 4-7 (pad 17)
    __shared__ __align__(16) float wq[8*TT*8];       // per-wave quarter sums
    __shared__ float rst[TT][16], wst[TT][16];       // own-row r and w = K@r
    __shared__ float sm[8][64];
    __shared__ float s_scale[TT], s_rhs[TT], s_al[TT], s_be[TT], s_ap[TT], s_gp[TT];
    __shared__ float redd[TT];

    const int t = threadIdx.x, b = blockIdx.x;
    const int lane = t & 63, w = t >> 6;             // 8 waves
    const int h = t >> 8;                            // row-half 0/1 (8 rows each)
    const int kslot = t & 255;                       // 16 k-floats per thread
    unsigned* bar = (unsigned*)(ws + O_BAR);
    float* r_ = ws + O_R;
    const float s2 = noise[0]*noise[0];
    int ph = 0;
    float pr = 0.f, sr = 0.f, xr = 0.f;              // per-thread CG state (t<272)

    // ---- one-time: K rows b*16+h*8+rr, k = g*1024 + kslot*4 -> 128 VGPRs ----
    float4 kreg[8][4];
    {
        const float* Kb = Km + (size_t)(b*16 + h*8)*NN + kslot*4;
        #pragma unroll
        for (int rr = 0; rr < 8; ++rr)
            #pragma unroll
            for (int g = 0; g < 4; ++g)
                kreg[rr][g] = *(const float4*)(Kb + (size_t)rr*NN + g*1024);
    }

    // ---- setup: per-column sum-of-squares partials (blocks 0..15) ----
    if (t < TT) redd[t] = 0.f;
    __syncthreads();
    if (b < 16 && t < 256) {
        int n = b*256 + t;
        float yy = yv[n];
        atomicAdd(&redd[0], yy*yy);
        #pragma unroll
        for (int j = 0; j < PP; ++j) { float v = Zm[n*PP + j]; atomicAdd(&redd[j+1], v*v); }
    }
    __syncthreads();
    if (b < 16 && t < TT)
        __hip_atomic_store(&ws[O_SSQ + b*64 + t], redd[t], RLX, AGENT);
    gridbar(bar, ph++, b);

    // ---- setup: scale/rhs replicated (cached reads, post-inv); r0 publish ----
    if (t < TT) {
        float s = 0.f;
        #pragma unroll
        for (int i = 0; i < 16; ++i) s += ws[O_SSQ + i*64 + t];
        float scale, rh;
        if (t == 0) {
            rh = sqrtf(s); if (rh < 1e-10f) rh = 1.f;
            scale = 1.f/rh;
        } else {
            float zn = sqrtf(s);
            float bn = zn/(zn + 1e-10f);
            rh = (bn < 1e-10f) ? 1.f : bn;
            scale = 1.f/((zn + 1e-10f)*rh);
        }
        s_scale[t] = scale; s_rhs[t] = rh;
    }
    __syncthreads();
    if (t < EPB) {
        int c = t >> 4, i = t & 15, n = b*16 + i;
        float raw = (c == 0) ? yv[n] : Zm[n*PP + (c-1)];
        __hip_atomic_store(&r_[c*NN + n], raw * s_scale[c], RLX, AGENT);
    }
    gridbar(bar, ph++, b);

    // ---- 47 CG iterations ----
    for (int it = 0; it < NIT; ++it) {
        // prologue: stage col 0 (16 KB) via CACHED loads; 16B-stride writes
        {
            const float* p0 = r_ + t*4;
            const float* p1 = r_ + 2048 + t*4;
            f32x4 a0, a1;
            asm volatile(
                "global_load_dwordx4 %0, %2, off\n\t"
                "global_load_dwordx4 %1, %3, off\n\t"
                "s_waitcnt vmcnt(0)"
                : "=&v"(a0), "=&v"(a1) : "v"(p0), "v"(p1) : "memory");
            *(f32x4*)&rslab[0][t*4]        = a0;
            *(f32x4*)&rslab[0][2048 + t*4] = a1;
        }
        __syncthreads();
        int cur = 0;

        for (int c = 0; c < TT; ++c) {
            // issue next col's cached loads early (L2/L3 latency hides)
            f32x4 sA, sB;
            const bool more = (c + 1 < TT);
            if (more) {
                const float* p0 = r_ + (c+1)*NN + t*4;
                const float* p1 = p0 + 2048;
                asm volatile(
                    "global_load_dwordx4 %0, %2, off\n\t"
                    "global_load_dwordx4 %1, %3, off"
                    : "=&v"(sA), "=&v"(sB) : "v"(p0), "v"(p1) : "memory");
            }
            if (t < 16) rst[c][t] = rslab[cur][b*16 + t];   // own-row r capture

            // compute: 4x ds_read_b128 + 128 fmac into 8 row-accs
            float acc[8];
            #pragma unroll
            for (int rr = 0; rr < 8; ++rr) acc[rr] = 0.f;
            const float* rc = &rslab[cur][kslot*4];
            #pragma unroll
            for (int g = 0; g < 4; ++g) {
                float4 rv = *(const float4*)(rc + g*1024);
                #pragma unroll
                for (int rr = 0; rr < 8; ++rr)
                    acc[rr] += kreg[rr][g].x*rv.x + kreg[rr][g].y*rv.y
                             + kreg[rr][g].z*rv.z + kreg[rr][g].w*rv.w;
            }
            // 2-stage butterfly: 64 lanes -> 16 lane-classes
            #pragma unroll
            for (int rr = 0; rr < 8; ++rr) {
                float v2 = acc[rr];
                v2 += __shfl_xor(v2, 32, 64);
                v2 += __shfl_xor(v2, 16, 64);
                acc[rr] = v2;
            }
            if (lane < 16) {
                p2a[(w*TT + c)*17 + lane] = make_float4(acc[0], acc[1], acc[2], acc[3]);
                p2b[(w*TT + c)*17 + lane] = make_float4(acc[4], acc[5], acc[6], acc[7]);
            }
            if (more) {
                asm volatile("s_waitcnt vmcnt(0)" ::: "memory");
                __builtin_amdgcn_sched_barrier(0);
                *(f32x4*)&rslab[cur^1][t*4]        = sA;
                *(f32x4*)&rslab[cur^1][2048 + t*4] = sB;
                __syncthreads();
                cur ^= 1;
            }
        }
        __syncthreads();                         // last col's p2 writes visible

        // finish: (w2,c2) sums 16 lane-classes -> wq[w2][c2][0..7] (no atomics)
        if (t < 8*TT) {
            int w2 = t / TT, c2 = t % TT;
            float4 sa = make_float4(0.f,0.f,0.f,0.f), sb = make_float4(0.f,0.f,0.f,0.f);
            #pragma unroll
            for (int i = 0; i < 16; ++i) {
                float4 u = p2a[(w2*TT + c2)*17 + i];
                sa.x += u.x; sa.y += u.y; sa.z += u.z; sa.w += u.w;
                float4 v2 = p2b[(w2*TT + c2)*17 + i];
                sb.x += v2.x; sb.y += v2.y; sb.z += v2.z; sb.w += v2.w;
            }
            float* wr = &wq[(w2*TT + c2)*8];
            *(float4*)(wr)     = sa;
            *(float4*)(wr + 4) = sb;
        }
        __syncthreads();

        // assemble wst[c][i] = sum of 4 k-quarters (deterministic order)
        if (t < EPB) {
            int c = t >> 4, i = t & 15, h2 = i >> 3, j = i & 7;
            float s = 0.f;
            #pragma unroll
            for (int q = 0; q < 4; ++q)
                s += wq[((h2*4 + q)*TT + c)*8 + j];
            wst[c][i] = s;
        }
        __syncthreads();

        // dp/gp fully local (own rows): publish 34 floats via sc1
        if (t < TT) {
            float dp = 0.f, gp = 0.f;
            #pragma unroll
            for (int i = 0; i < 16; ++i) {
                float rv = rst[t][i];
                dp += rv * wst[t][i];
                gp += rv * rv;
            }
            __hip_atomic_store(&ws[O_SLOT + b*64 + t], dp, RLX, AGENT);
            __hip_atomic_store(&ws[O_SLOT + b*64 + 32 + t], gp, RLX, AGENT);
        }
        gridbar(bar, ph++, b);

        // phase B: slot reduce via CACHED loads (post-inv), alpha/beta, update
        {
            int seg = t >> 6, j = t & 63;
            float s = 0.f;
            if (j < TT || (j >= 32 && j < 32 + TT)) {
                #pragma unroll
                for (int i = 0; i < 32; ++i)
                    s += ws[O_SLOT + (seg*32 + i)*64 + j];
            }
            sm[seg][j] = s;
        }
        __syncthreads();
        if (t < TT) {
            float del = 0.f, gam = 0.f;
            #pragma unroll
            for (int g = 0; g < 8; ++g) { del += sm[g][t]; gam += sm[g][32 + t]; }
            float delta = del + s2*gam;          // r^T (K + s2 I) r
            float beta = 0.f, D = delta;
            if (it > 0) {
                float gpv = s_gp[t];
                beta = (fabsf(gpv) < 1e-30f) ? 0.f : gam/gpv;
                float apv = s_ap[t];
                D = delta - ((fabsf(apv) < 1e-30f) ? 0.f : beta*gam/apv);
            }
            float alpha = (fabsf(D) < 1e-30f) ? 0.f : gam/D;
            s_al[t] = alpha; s_be[t] = beta; s_ap[t] = alpha; s_gp[t] = gam;
        }
        __syncthreads();
        if (t < EPB) {
            int c = t >> 4, i = t & 15;
            float al = s_al[c], be = s_be[c];
            float rv = rst[c][i];
            float wv = wst[c][i] + s2*rv;
            pr = rv + be*pr;
            sr = wv + be*sr;
            xr = xr + al*pr;
            float rn = rv - al*sr;
            __hip_atomic_store(&r_[c*NN + b*16 + i], rn, RLX, AGENT);
            if (it == NIT-1) out[(b*16 + i)*TT + c] = xr * s_rhs[c];
        }
        gridbar(bar, ph++, b);
    }
}

extern "C" void kernel_launch(void* const* d_in, const int* in_sizes, int n_in,
                              void* d_out, int out_size, void* d_ws, size_t ws_size,
                              hipStream_t stream) {
    const float* Km    = (const float*)d_in[0];
    const float* yv    = (const float*)d_in[1];
    const float* Zm    = (const float*)d_in[2];
    const float* noise = (const float*)d_in[3];
    float* out = (float*)d_out;
    float* ws  = (float*)d_ws;

    k_bzero<<<1, 576, 0, stream>>>(ws);
    void* args[] = {(void*)&Km, (void*)&yv, (void*)&Zm, (void*)&noise,
                    (void*)&out, (void*)&ws};
    (void)hipLaunchCooperativeKernel((const void*)k_cg, dim3(NBLK), dim3(NTHR),
                                     args, 0, stream);
}

// Round 10
// 1267.127 us; speedup vs baseline: 1.3550x; 1.3550x over previous
//
#include <hip/hip_runtime.h>

// Persistent-CG, full-row decomposition. R9 post-mortem: cached-read+inv ≈ sc1
// reads (1717 vs 1604) -> no single data stream dominates; inv fence alone cost
// +110us. R6≈R8≈R9 at ~34us/iter vs ~7us VALU => residual = exposed L3 latency
// per staged column + slot-reduce request storm + 2 gridbars.
// R10: (1) revert to pure-sc1 reads, NO inv (R8 path, best measured);
// (2) depth-3 r prefetch, counted vmcnt(2) never 0 mid-loop -> col stage latency
// covered by ~2 columns of compute; (3) slots transposed to [64][256], phase B
// reads 8x dwordx4 contiguous per thread (4x fewer coherence-point requests).
// Keeps R9's wq no-atomic finish (bank conflicts 26.5M->1.1M verified).

#define NN   4096
#define TT   17
#define PP   16
#define NTOT (NN*TT)
#define NIT  47
#define NBLK 256              // 1 block/CU, cooperative co-residency
#define NTHR 512              // 8 waves
#define EPB  272              // 17 cols x 16 own rows

// ws float offsets
#define O_SSQ  0                    // [16][64] setup ssq partials (sc1 path)
#define O_SLOT (O_SSQ + 16*64)      // [64 cols][256 blocks] dot slots (sc1 path)
#define O_BAR  (O_SLOT + 64*256)    // flags[256] + go replicas at 256+32*i
#define O_R    (O_BAR + 576)        // r (sc1 path)

#define AGENT __HIP_MEMORY_SCOPE_AGENT
#define RLX   __ATOMIC_RELAXED

typedef float f32x4 __attribute__((ext_vector_type(4)));

__global__ void k_bzero(float* __restrict__ ws) {
    if (threadIdx.x < 576) ((unsigned*)(ws + O_BAR))[threadIdx.x] = 0u;
}

// Store-only monotonic grid barrier (R6/R8-verified, NO exit fence). Entry
// waitcnt drains sc1 stores to the coherence point; consumers use sc1 loads.
__device__ __forceinline__ void gridbar(unsigned* bar, int phase, int b) {
    const unsigned target = (unsigned)(phase + 1);
    asm volatile("s_waitcnt vmcnt(0)" ::: "memory");
    __syncthreads();
    if (b == 0) {
        if (threadIdx.x >= 1 && threadIdx.x < NBLK) {
            while (__hip_atomic_load(&bar[threadIdx.x], RLX, AGENT) < target)
                __builtin_amdgcn_s_sleep(1);
        }
        __syncthreads();
        if (threadIdx.x < 8)
            __hip_atomic_store(&bar[256 + threadIdx.x*32], target, RLX, AGENT);
    } else {
        if (threadIdx.x == 0) {
            __hip_atomic_store(&bar[b], target, RLX, AGENT);
            while (__hip_atomic_load(&bar[256 + (b & 7)*32], RLX, AGENT) < target)
                __builtin_amdgcn_s_sleep(1);
        }
    }
    __syncthreads();
}

// issue one r-column's 2 sc1 loads (no wait) into dA/dB
#define ISSUE_COL(cc, dA, dB) do {                                   \
    const float* _p0 = r_ + (size_t)(cc)*NN + t*4;                   \
    const float* _p1 = _p0 + 2048;                                   \
    asm volatile("global_load_dwordx4 %0, %2, off sc1\n\t"           \
                 "global_load_dwordx4 %1, %3, off sc1"               \
                 : "=&v"(dA), "=&v"(dB) : "v"(_p0), "v"(_p1)         \
                 : "memory");                                        \
} while (0)

__global__ __launch_bounds__(NTHR, 2)
void k_cg(const float* __restrict__ Km, const float* __restrict__ yv,
          const float* __restrict__ Zm, const float* __restrict__ noise,
          float* __restrict__ out, float* __restrict__ ws) {
    __shared__ __align__(16) float rslab[3][NN];     // 48 KB, depth-3 pipeline
    __shared__ float4 p2a[8*TT*17];                  // wave partials rows 0-3
    __shared__ float4 p2b[8*TT*17];                  // rows 4-7 (pad 17)
    __shared__ __align__(16) float wq[8*TT*8];       // per-wave quarter sums
    __shared__ float rst[TT][16], wst[TT][16];       // own-row r and w = K@r
    __shared__ float sm2[34][8], s_dg[34];
    __shared__ float s_scale[TT], s_rhs[TT], s_al[TT], s_be[TT], s_ap[TT], s_gp[TT];
    __shared__ float redd[TT];

    const int t = threadIdx.x, b = blockIdx.x;
    const int lane = t & 63, w = t >> 6;             // 8 waves
    const int h = t >> 8;                            // row-half 0/1 (8 rows each)
    const int kslot = t & 255;                       // 16 k-floats per thread
    unsigned* bar = (unsigned*)(ws + O_BAR);
    float* r_ = ws + O_R;
    const float s2 = noise[0]*noise[0];
    int ph = 0;
    float pr = 0.f, sr = 0.f, xr = 0.f;              // per-thread CG state (t<272)

    // ---- one-time: K rows b*16+h*8+rr, k = g*1024 + kslot*4 -> 128 VGPRs ----
    float4 kreg[8][4];
    {
        const float* Kb = Km + (size_t)(b*16 + h*8)*NN + kslot*4;
        #pragma unroll
        for (int rr = 0; rr < 8; ++rr)
            #pragma unroll
            for (int g = 0; g < 4; ++g)
                kreg[rr][g] = *(const float4*)(Kb + (size_t)rr*NN + g*1024);
    }

    // ---- setup: per-column sum-of-squares partials (blocks 0..15) ----
    if (t < TT) redd[t] = 0.f;
    __syncthreads();
    if (b < 16 && t < 256) {
        int n = b*256 + t;
        float yy = yv[n];
        atomicAdd(&redd[0], yy*yy);
        #pragma unroll
        for (int j = 0; j < PP; ++j) { float v = Zm[n*PP + j]; atomicAdd(&redd[j+1], v*v); }
    }
    __syncthreads();
    if (b < 16 && t < TT)
        __hip_atomic_store(&ws[O_SSQ + b*64 + t], redd[t], RLX, AGENT);
    gridbar(bar, ph++, b);

    // ---- setup: scale/rhs replicated (sc1 reads); r0 publish ----
    if (t < TT) {
        float s = 0.f;
        #pragma unroll
        for (int i = 0; i < 16; ++i)
            s += __hip_atomic_load(&ws[O_SSQ + i*64 + t], RLX, AGENT);
        float scale, rh;
        if (t == 0) {
            rh = sqrtf(s); if (rh < 1e-10f) rh = 1.f;
            scale = 1.f/rh;
        } else {
            float zn = sqrtf(s);
            float bn = zn/(zn + 1e-10f);
            rh = (bn < 1e-10f) ? 1.f : bn;
            scale = 1.f/((zn + 1e-10f)*rh);
        }
        s_scale[t] = scale; s_rhs[t] = rh;
    }
    __syncthreads();
    if (t < EPB) {
        int c = t >> 4, i = t & 15, n = b*16 + i;
        float raw = (c == 0) ? yv[n] : Zm[n*PP + (c-1)];
        __hip_atomic_store(&r_[c*NN + n], raw * s_scale[c], RLX, AGENT);
    }
    gridbar(bar, ph++, b);

    // ---- 47 CG iterations ----
    for (int it = 0; it < NIT; ++it) {
        f32x4 sv[3][2];
        // prologue: issue cols 0,1; wait col0 pair (vmcnt(2)); write slab 0
        ISSUE_COL(0, sv[0][0], sv[0][1]);
        ISSUE_COL(1, sv[1][0], sv[1][1]);
        asm volatile("s_waitcnt vmcnt(2)" ::: "memory");
        __builtin_amdgcn_sched_barrier(0);
        *(f32x4*)&rslab[0][t*4]        = sv[0][0];
        *(f32x4*)&rslab[0][2048 + t*4] = sv[0][1];
        __syncthreads();

        #pragma unroll
        for (int c = 0; c < TT; ++c) {
            if (c + 2 < TT) ISSUE_COL(c+2, sv[(c+2)%3][0], sv[(c+2)%3][1]);
            if (t < 16) rst[c][t] = rslab[c%3][b*16 + t];   // own-row r capture

            // compute: 4x ds_read_b128 + 128 fmac into 8 row-accs
            float acc[8];
            #pragma unroll
            for (int rr = 0; rr < 8; ++rr) acc[rr] = 0.f;
            const float* rc = &rslab[c%3][kslot*4];
            #pragma unroll
            for (int g = 0; g < 4; ++g) {
                float4 rv = *(const float4*)(rc + g*1024);
                #pragma unroll
                for (int rr = 0; rr < 8; ++rr)
                    acc[rr] += kreg[rr][g].x*rv.x + kreg[rr][g].y*rv.y
                             + kreg[rr][g].z*rv.z + kreg[rr][g].w*rv.w;
            }
            // 2-stage butterfly: 64 lanes -> 16 lane-classes
            #pragma unroll
            for (int rr = 0; rr < 8; ++rr) {
                float v2 = acc[rr];
                v2 += __shfl_xor(v2, 32, 64);
                v2 += __shfl_xor(v2, 16, 64);
                acc[rr] = v2;
            }
            if (lane < 16) {
                p2a[(w*TT + c)*17 + lane] = make_float4(acc[0], acc[1], acc[2], acc[3]);
                p2b[(w*TT + c)*17 + lane] = make_float4(acc[4], acc[5], acc[6], acc[7]);
            }
            if (c + 1 < TT) {
                if (c + 2 < TT) { asm volatile("s_waitcnt vmcnt(2)" ::: "memory"); }
                else            { asm volatile("s_waitcnt vmcnt(0)" ::: "memory"); }
                __builtin_amdgcn_sched_barrier(0);
                *(f32x4*)&rslab[(c+1)%3][t*4]        = sv[(c+1)%3][0];
                *(f32x4*)&rslab[(c+1)%3][2048 + t*4] = sv[(c+1)%3][1];
                __syncthreads();
            }
        }
        __syncthreads();                         // last col's p2 writes visible

        // finish: (w2,c2) sums 16 lane-classes -> wq[w2][c2][0..7] (no atomics)
        if (t < 8*TT) {
            int w2 = t / TT, c2 = t % TT;
            float4 sa = make_float4(0.f,0.f,0.f,0.f), sb = make_float4(0.f,0.f,0.f,0.f);
            #pragma unroll
            for (int i = 0; i < 16; ++i) {
                float4 u = p2a[(w2*TT + c2)*17 + i];
                sa.x += u.x; sa.y += u.y; sa.z += u.z; sa.w += u.w;
                float4 v2 = p2b[(w2*TT + c2)*17 + i];
                sb.x += v2.x; sb.y += v2.y; sb.z += v2.z; sb.w += v2.w;
            }
            float* wr = &wq[(w2*TT + c2)*8];
            *(float4*)(wr)     = sa;
            *(float4*)(wr + 4) = sb;
        }
        __syncthreads();

        // assemble wst[c][i] = sum of 4 wave-quarters (deterministic order)
        if (t < EPB) {
            int c = t >> 4, i = t & 15, h2 = i >> 3, j = i & 7;
            float s = 0.f;
            #pragma unroll
            for (int q = 0; q < 4; ++q)
                s += wq[((h2*4 + q)*TT + c)*8 + j];
            wst[c][i] = s;
        }
        __syncthreads();

        // dp/gp fully local (own rows): publish to transposed slots [64][256]
        if (t < TT) {
            float dp = 0.f, gp = 0.f;
            #pragma unroll
            for (int i = 0; i < 16; ++i) {
                float rv = rst[t][i];
                dp += rv * wst[t][i];
                gp += rv * rv;
            }
            __hip_atomic_store(&ws[O_SLOT + t*256 + b], dp, RLX, AGENT);
            __hip_atomic_store(&ws[O_SLOT + (32 + t)*256 + b], gp, RLX, AGENT);
        }
        gridbar(bar, ph++, b);

        // phase B: transposed slot reduce -- 8x dwordx4 sc1 per active thread
        if (t < 272) {
            int jdx = t >> 3, q = t & 7;
            int j = jdx + ((jdx >= 17) ? 15 : 0);   // 0..16 -> dp, 32..48 -> gp
            const float* sp = ws + O_SLOT + j*256 + q*32;
            f32x4 v0, v1, v2, v3, v4, v5, v6, v7;
            asm volatile(
                "global_load_dwordx4 %0, %8, off sc1\n\t"
                "global_load_dwordx4 %1, %8, off offset:16 sc1\n\t"
                "global_load_dwordx4 %2, %8, off offset:32 sc1\n\t"
                "global_load_dwordx4 %3, %8, off offset:48 sc1\n\t"
                "global_load_dwordx4 %4, %8, off offset:64 sc1\n\t"
                "global_load_dwordx4 %5, %8, off offset:80 sc1\n\t"
                "global_load_dwordx4 %6, %8, off offset:96 sc1\n\t"
                "global_load_dwordx4 %7, %8, off offset:112 sc1\n\t"
                "s_waitcnt vmcnt(0)"
                : "=&v"(v0), "=&v"(v1), "=&v"(v2), "=&v"(v3),
                  "=&v"(v4), "=&v"(v5), "=&v"(v6), "=&v"(v7)
                : "v"(sp) : "memory");
            f32x4 s = ((v0 + v1) + (v2 + v3)) + ((v4 + v5) + (v6 + v7));
            sm2[jdx][q] = (s.x + s.y) + (s.z + s.w);
        }
        __syncthreads();
        if (t < 34) {
            float g = 0.f;
            #pragma unroll
            for (int q = 0; q < 8; ++q) g += sm2[t][q];
            s_dg[t] = g;
        }
        __syncthreads();
        if (t < TT) {
            float del = s_dg[t], gam = s_dg[17 + t];
            float delta = del + s2*gam;          // r^T (K + s2 I) r
            float beta = 0.f, D = delta;
            if (it > 0) {
                float gpv = s_gp[t];
                beta = (fabsf(gpv) < 1e-30f) ? 0.f : gam/gpv;
                float apv = s_ap[t];
                D = delta - ((fabsf(apv) < 1e-30f) ? 0.f : beta*gam/apv);
            }
            float alpha = (fabsf(D) < 1e-30f) ? 0.f : gam/D;
            s_al[t] = alpha; s_be[t] = beta; s_ap[t] = alpha; s_gp[t] = gam;
        }
        __syncthreads();
        if (t < EPB) {
            int c = t >> 4, i = t & 15;
            float al = s_al[c], be = s_be[c];
            float rv = rst[c][i];
            float wv = wst[c][i] + s2*rv;
            pr = rv + be*pr;
            sr = wv + be*sr;
            xr = xr + al*pr;
            float rn = rv - al*sr;
            __hip_atomic_store(&r_[c*NN + b*16 + i], rn, RLX, AGENT);
            if (it == NIT-1) out[(b*16 + i)*TT + c] = xr * s_rhs[c];
        }
        gridbar(bar, ph++, b);
    }
}

extern "C" void kernel_launch(void* const* d_in, const int* in_sizes, int n_in,
                              void* d_out, int out_size, void* d_ws, size_t ws_size,
                              hipStream_t stream) {
    const float* Km    = (const float*)d_in[0];
    const float* yv    = (const float*)d_in[1];
    const float* Zm    = (const float*)d_in[2];
    const float* noise = (const float*)d_in[3];
    float* out = (float*)d_out;
    float* ws  = (float*)d_ws;

    k_bzero<<<1, 576, 0, stream>>>(ws);
    void* args[] = {(void*)&Km, (void*)&yv, (void*)&Zm, (void*)&noise,
                    (void*)&out, (void*)&ws};
    (void)hipLaunchCooperativeKernel((const void*)k_cg, dim3(NBLK), dim3(NTHR),
                                     args, 0, stream);
}

// Round 11
// 1002.356 us; speedup vs baseline: 1.7129x; 1.2641x over previous
//
#include <hip/hip_runtime.h>

// Persistent-CG, full-row decomposition. R10 post-mortem (1267us, pred 1200-1400
// CONFIRMED): inv-removal/depth-3/slot-transpose all real. Residual ~21us/iter:
// sc1 r-broadcast (68MB/iter raw 16B requests, no cache aggregation), 17
// per-column syncthreads+LDS slab, 2 gridbars, slot storm.
// R11: VERSIONED buffers. Each iter writes r (and slots) to a fresh 128B-aligned
// generation region (48 gens). Writes stay sc1 write-through (never dirty in L2);
// reads become PLAIN CACHED loads -- virgin lines can't be stale anywhere, so no
// inv fence (R9: inv = +110us). Per-XCD L2 fetches each r line once from L3
// (2.2MB/iter vs 68MB bypass); 31 other blocks L2-hit. GEMM goes direct-to-
// register (thread loads exactly its 4xfloat4 of r): LDS slab staging and all
// 17 per-column syncthreads deleted. Arithmetic order identical to R10.

#define NN   4096
#define TT   17
#define PP   16
#define NTOT (NN*TT)          // 69632 floats/gen, 128B-aligned (69632*4 % 128 == 0)
#define NIT  47
#define NGEN 48
#define SLOTG (64*256)        // 16384 floats/gen, 128B-aligned
#define NBLK 256              // 1 block/CU, cooperative co-residency
#define NTHR 512              // 8 waves
#define EPB  272              // 17 cols x 16 own rows

// ws float offsets (all 32-float = 128B aligned)
#define O_SSQ  0                        // [16][64] setup ssq partials (sc1 path)
#define O_BAR  1024                     // flags[256] + go replicas; 576 slots
#define O_SLOT 1600                     // [48 gens][64][256] dot slots
#define O_R    (O_SLOT + NGEN*SLOTG)    // [48 gens][NTOT] r
// total: 1600 + 48*16384 + 48*69632 = 4,130,368 floats = 15.8 MB

#define AGENT __HIP_MEMORY_SCOPE_AGENT
#define RLX   __ATOMIC_RELAXED

typedef float f32x4 __attribute__((ext_vector_type(4)));

__global__ void k_bzero(float* __restrict__ ws) {
    if (threadIdx.x < 576) ((unsigned*)(ws + O_BAR))[threadIdx.x] = 0u;
}

// Store-only monotonic grid barrier (R6/R8/R10-verified, NO exit fence).
__device__ __forceinline__ void gridbar(unsigned* bar, int phase, int b) {
    const unsigned target = (unsigned)(phase + 1);
    asm volatile("s_waitcnt vmcnt(0)" ::: "memory");   // sc1 stores drained to L3
    __syncthreads();
    if (b == 0) {
        if (threadIdx.x >= 1 && threadIdx.x < NBLK) {
            while (__hip_atomic_load(&bar[threadIdx.x], RLX, AGENT) < target)
                __builtin_amdgcn_s_sleep(1);
        }
        __syncthreads();
        if (threadIdx.x < 8)
            __hip_atomic_store(&bar[256 + threadIdx.x*32], target, RLX, AGENT);
    } else {
        if (threadIdx.x == 0) {
            __hip_atomic_store(&bar[b], target, RLX, AGENT);
            while (__hip_atomic_load(&bar[256 + (b & 7)*32], RLX, AGENT) < target)
                __builtin_amdgcn_s_sleep(1);
        }
    }
    __syncthreads();
}

__global__ __launch_bounds__(NTHR, 2)
void k_cg(const float* __restrict__ Km, const float* __restrict__ yv,
          const float* __restrict__ Zm, const float* __restrict__ noise,
          float* __restrict__ out, float* __restrict__ ws) {
    __shared__ float4 p2a[8*TT*17];                  // wave partials rows 0-3
    __shared__ float4 p2b[8*TT*17];                  // rows 4-7 (pad 17)
    __shared__ __align__(16) float wq[8*TT*8];       // per-wave quarter sums
    __shared__ float rst[TT][16], wst[TT][16];       // own-row r and w = K@r
    __shared__ float sm2[34][8], s_dg[34];
    __shared__ float s_scale[TT], s_rhs[TT], s_al[TT], s_be[TT], s_ap[TT], s_gp[TT];
    __shared__ float redd[TT];

    const int t = threadIdx.x, b = blockIdx.x;
    const int lane = t & 63, w = t >> 6;             // 8 waves
    const int h = t >> 8;                            // row-half 0/1 (8 rows each)
    const int kslot = t & 255;                       // 16 k-floats per thread
    unsigned* bar = (unsigned*)(ws + O_BAR);
    const float s2 = noise[0]*noise[0];
    int ph = 0;
    float pr = 0.f, sr = 0.f, xr = 0.f;              // per-thread CG state (t<272)

    // ---- one-time: K rows b*16+h*8+rr, k = g*1024 + kslot*4 -> 128 VGPRs ----
    float4 kreg[8][4];
    {
        const float* Kb = Km + (size_t)(b*16 + h*8)*NN + kslot*4;
        #pragma unroll
        for (int rr = 0; rr < 8; ++rr)
            #pragma unroll
            for (int g = 0; g < 4; ++g)
                kreg[rr][g] = *(const float4*)(Kb + (size_t)rr*NN + g*1024);
    }

    // ---- setup: per-column sum-of-squares partials (blocks 0..15) ----
    if (t < TT) redd[t] = 0.f;
    __syncthreads();
    if (b < 16 && t < 256) {
        int n = b*256 + t;
        float yy = yv[n];
        atomicAdd(&redd[0], yy*yy);
        #pragma unroll
        for (int j = 0; j < PP; ++j) { float v = Zm[n*PP + j]; atomicAdd(&redd[j+1], v*v); }
    }
    __syncthreads();
    if (b < 16 && t < TT)
        __hip_atomic_store(&ws[O_SSQ + b*64 + t], redd[t], RLX, AGENT);
    gridbar(bar, ph++, b);

    // ---- setup: scale/rhs replicated (sc1 reads); r gen-0 publish ----
    if (t < TT) {
        float s = 0.f;
        #pragma unroll
        for (int i = 0; i < 16; ++i)
            s += __hip_atomic_load(&ws[O_SSQ + i*64 + t], RLX, AGENT);
        float scale, rh;
        if (t == 0) {
            rh = sqrtf(s); if (rh < 1e-10f) rh = 1.f;
            scale = 1.f/rh;
        } else {
            float zn = sqrtf(s);
            float bn = zn/(zn + 1e-10f);
            rh = (bn < 1e-10f) ? 1.f : bn;
            scale = 1.f/((zn + 1e-10f)*rh);
        }
        s_scale[t] = scale; s_rhs[t] = rh;
    }
    __syncthreads();
    if (t < EPB) {
        int c = t >> 4, i = t & 15, n = b*16 + i;
        float raw = (c == 0) ? yv[n] : Zm[n*PP + (c-1)];
        __hip_atomic_store(&ws[O_R + c*NN + n], raw * s_scale[c], RLX, AGENT);
    }
    gridbar(bar, ph++, b);

    // ---- 47 CG iterations ----
    for (int it = 0; it < NIT; ++it) {
        const float* rg = ws + O_R + it*NTOT;        // this iter's r generation

        // own-row r capture: 272 cached scalar loads (virgin gen lines)
        if (t < EPB) rst[t >> 4][t & 15] = rg[(t >> 4)*NN + b*16 + (t & 15)];

        // GEMM: direct-to-register, software-pipelined over 17 columns.
        // Thread's operands: rg[c*NN + kslot*4 + g*1024], g=0..3 (cached loads;
        // L1 dedups the t/t+256 overlap; per-XCD L2 refills each line once).
        const float* rcb = rg + kslot*4;
        float4 cu0 = *(const float4*)(rcb);
        float4 cu1 = *(const float4*)(rcb + 1024);
        float4 cu2 = *(const float4*)(rcb + 2048);
        float4 cu3 = *(const float4*)(rcb + 3072);
        #pragma unroll 1
        for (int c = 0; c < TT; ++c) {
            float4 nx0, nx1, nx2, nx3;
            if (c + 1 < TT) {
                const float* rn = rcb + (c+1)*NN;
                nx0 = *(const float4*)(rn);
                nx1 = *(const float4*)(rn + 1024);
                nx2 = *(const float4*)(rn + 2048);
                nx3 = *(const float4*)(rn + 3072);
            }
            float acc[8];
            #pragma unroll
            for (int rr = 0; rr < 8; ++rr) acc[rr] = 0.f;
            #pragma unroll
            for (int rr = 0; rr < 8; ++rr)
                acc[rr] += kreg[rr][0].x*cu0.x + kreg[rr][0].y*cu0.y
                         + kreg[rr][0].z*cu0.z + kreg[rr][0].w*cu0.w;
            #pragma unroll
            for (int rr = 0; rr < 8; ++rr)
                acc[rr] += kreg[rr][1].x*cu1.x + kreg[rr][1].y*cu1.y
                         + kreg[rr][1].z*cu1.z + kreg[rr][1].w*cu1.w;
            #pragma unroll
            for (int rr = 0; rr < 8; ++rr)
                acc[rr] += kreg[rr][2].x*cu2.x + kreg[rr][2].y*cu2.y
                         + kreg[rr][2].z*cu2.z + kreg[rr][2].w*cu2.w;
            #pragma unroll
            for (int rr = 0; rr < 8; ++rr)
                acc[rr] += kreg[rr][3].x*cu3.x + kreg[rr][3].y*cu3.y
                         + kreg[rr][3].z*cu3.z + kreg[rr][3].w*cu3.w;
            // 2-stage butterfly: 64 lanes -> 16 lane-classes (order = R10)
            #pragma unroll
            for (int rr = 0; rr < 8; ++rr) {
                float v2 = acc[rr];
                v2 += __shfl_xor(v2, 32, 64);
                v2 += __shfl_xor(v2, 16, 64);
                acc[rr] = v2;
            }
            if (lane < 16) {
                p2a[(w*TT + c)*17 + lane] = make_float4(acc[0], acc[1], acc[2], acc[3]);
                p2b[(w*TT + c)*17 + lane] = make_float4(acc[4], acc[5], acc[6], acc[7]);
            }
            cu0 = nx0; cu1 = nx1; cu2 = nx2; cu3 = nx3;
        }
        __syncthreads();                         // all waves' p2 writes visible

        // finish: (w2,c2) sums 16 lane-classes -> wq[w2][c2][0..7] (no atomics)
        if (t < 8*TT) {
            int w2 = t / TT, c2 = t % TT;
            float4 sa = make_float4(0.f,0.f,0.f,0.f), sb = make_float4(0.f,0.f,0.f,0.f);
            #pragma unroll
            for (int i = 0; i < 16; ++i) {
                float4 u = p2a[(w2*TT + c2)*17 + i];
                sa.x += u.x; sa.y += u.y; sa.z += u.z; sa.w += u.w;
                float4 v2 = p2b[(w2*TT + c2)*17 + i];
                sb.x += v2.x; sb.y += v2.y; sb.z += v2.z; sb.w += v2.w;
            }
            float* wr = &wq[(w2*TT + c2)*8];
            *(float4*)(wr)     = sa;
            *(float4*)(wr + 4) = sb;
        }
        __syncthreads();

        // assemble wst[c][i] = sum of 4 wave-quarters (deterministic order)
        if (t < EPB) {
            int c = t >> 4, i = t & 15, h2 = i >> 3, j = i & 7;
            float s = 0.f;
            #pragma unroll
            for (int q = 0; q < 4; ++q)
                s += wq[((h2*4 + q)*TT + c)*8 + j];
            wst[c][i] = s;
        }
        __syncthreads();

        // dp/gp fully local (own rows): publish to THIS gen's slots via sc1
        if (t < TT) {
            float dp = 0.f, gp = 0.f;
            #pragma unroll
            for (int i = 0; i < 16; ++i) {
                float rv = rst[t][i];
                dp += rv * wst[t][i];
                gp += rv * rv;
            }
            float* sl = ws + O_SLOT + it*SLOTG;
            __hip_atomic_store(&sl[t*256 + b], dp, RLX, AGENT);
            __hip_atomic_store(&sl[(32 + t)*256 + b], gp, RLX, AGENT);
        }
        gridbar(bar, ph++, b);

        // phase B: slot reduce via CACHED float4 reads (virgin gen lines)
        if (t < 272) {
            int jdx = t >> 3, q = t & 7;
            int j = jdx + ((jdx >= 17) ? 15 : 0);   // 0..16 -> dp, 32..48 -> gp
            const float* sp = ws + O_SLOT + it*SLOTG + j*256 + q*32;
            float4 v0 = *(const float4*)(sp);
            float4 v1 = *(const float4*)(sp + 4);
            float4 v2 = *(const float4*)(sp + 8);
            float4 v3 = *(const float4*)(sp + 12);
            float4 v4 = *(const float4*)(sp + 16);
            float4 v5 = *(const float4*)(sp + 20);
            float4 v6 = *(const float4*)(sp + 24);
            float4 v7 = *(const float4*)(sp + 28);
            float sx = ((v0.x+v1.x)+(v2.x+v3.x)) + ((v4.x+v5.x)+(v6.x+v7.x));
            float sy = ((v0.y+v1.y)+(v2.y+v3.y)) + ((v4.y+v5.y)+(v6.y+v7.y));
            float sz = ((v0.z+v1.z)+(v2.z+v3.z)) + ((v4.z+v5.z)+(v6.z+v7.z));
            float sw = ((v0.w+v1.w)+(v2.w+v3.w)) + ((v4.w+v5.w)+(v6.w+v7.w));
            sm2[jdx][q] = (sx + sy) + (sz + sw);
        }
        __syncthreads();
        if (t < 34) {
            float g = 0.f;
            #pragma unroll
            for (int q = 0; q < 8; ++q) g += sm2[t][q];
            s_dg[t] = g;
        }
        __syncthreads();
        if (t < TT) {
            float del = s_dg[t], gam = s_dg[17 + t];
            float delta = del + s2*gam;          // r^T (K + s2 I) r
            float beta = 0.f, D = delta;
            if (it > 0) {
                float gpv = s_gp[t];
                beta = (fabsf(gpv) < 1e-30f) ? 0.f : gam/gpv;
                float apv = s_ap[t];
                D = delta - ((fabsf(apv) < 1e-30f) ? 0.f : beta*gam/apv);
            }
            float alpha = (fabsf(D) < 1e-30f) ? 0.f : gam/D;
            s_al[t] = alpha; s_be[t] = beta; s_ap[t] = alpha; s_gp[t] = gam;
        }
        __syncthreads();
        if (t < EPB) {
            int c = t >> 4, i = t & 15;
            float al = s_al[c], be = s_be[c];
            float rv = rst[c][i];
            float wv = wst[c][i] + s2*rv;
            pr = rv + be*pr;
            sr = wv + be*sr;
            xr = xr + al*pr;
            float rn = rv - al*sr;
            if (it < NIT-1)
                __hip_atomic_store(&ws[O_R + (it+1)*NTOT + c*NN + b*16 + i],
                                   rn, RLX, AGENT);
            else
                out[(b*16 + i)*TT + c] = xr * s_rhs[c];
        }
        gridbar(bar, ph++, b);
    }
}

extern "C" void kernel_launch(void* const* d_in, const int* in_sizes, int n_in,
                              void* d_out, int out_size, void* d_ws, size_t ws_size,
                              hipStream_t stream) {
    const float* Km    = (const float*)d_in[0];
    const float* yv    = (const float*)d_in[1];
    const float* Zm    = (const float*)d_in[2];
    const float* noise = (const float*)d_in[3];
    float* out = (float*)d_out;
    float* ws  = (float*)d_ws;

    k_bzero<<<1, 576, 0, stream>>>(ws);
    void* args[] = {(void*)&Km, (void*)&yv, (void*)&Zm, (void*)&noise,
                    (void*)&out, (void*)&ws};
    (void)hipLaunchCooperativeKernel((const void*)k_cg, dim3(NBLK), dim3(NTHR),
                                     args, 0, stream);
}